// Round 5
// baseline (393.923 us; speedup 1.0000x reference)
//
#include <hip/hip_runtime.h>

// CASSI forward: out[b,l,m,n] = phi[m,n] * y2[b,m,2l+n]
//   y2[b,m,k] = sum_{l'} x[b,l',m,k-2l'] * phi[m,k-2l'],  0 <= k-2l' < N
// M=N=512, L=28, B=8, STRIDE=2, n_out = 566.
//
// History: R3 aligned-quad kernel ~99-105us. R4 LDS swizzle regressed.
// R5 L-split regressed (occupancy not the limiter). R6 one-row blocks
// neutral (not convoy-bound). R7 two-kernel split neutral in kernel time
// (write-scatter not the limiter).
//
// R8: last untested mechanism -- kernel B's ~500 MB of cache reads (phi
// 235MB L2-traffic + y2 264MB L3-traffic) interleaved with its NT write
// stream; the fill (6.6 TB/s) has zero reads. New B: block = (b, 8 m-rows,
// ALL 28 l), 1024 threads. Stage 8 y2 rows (18.4 KB) in LDS once, hoist
// phi quad to regs once, then 28 x 16KB perfectly contiguous NT bursts
// fed only from LDS/regs. Kernel A unchanged (attribution).

#define M_DIM 512
#define N_DIM 512
#define L_DIM 28
#define B_DIM 8
#define MN_DIM (M_DIM * N_DIM)
#define NT 14       // tail quads (k = 512+4t, t<14)
#define U_DIM 14    // l-pairs (l = 2u, 2u+1)
#define YSTRIDE 576 // y2 row stride in floats (2304 B, 16B-aligned)
#define MB 8        // m-rows per kernel-B block

typedef float v2f __attribute__((ext_vector_type(2)));
typedef float v4f __attribute__((ext_vector_type(4)));

// ---------------- Kernel A: y2 = scatter-accumulate(x * phi) ----------------
__global__ __launch_bounds__(128) void cassi_y2_kernel(
    const float* __restrict__ x, const float* __restrict__ phi,
    float* __restrict__ y2w)
{
    __shared__ __align__(16) float sphi[N_DIM];

    const int t  = threadIdx.x;      // quad owner within row, 0..127
    const int bm = blockIdx.x;       // 0..4095
    const int b  = bm >> 9;
    const int m  = bm & 511;

    const float* xrow = x + (size_t)b * L_DIM * MN_DIM + (size_t)m * N_DIM;

    v4f pq = *(const v4f*)(phi + (size_t)m * N_DIM + 4 * t);
    *(v4f*)&sphi[4 * t] = pq;
    __syncthreads();

    const bool lane0 = ((t & 63) == 0);

    v4f acc  = {0.f, 0.f, 0.f, 0.f};
    v4f acct = {0.f, 0.f, 0.f, 0.f};

#pragma unroll
    for (int u = 0; u < U_DIM; ++u) {
        const int s  = t - u;
        const int sc = s < 0 ? 0 : s;
        const float* re = xrow + (size_t)(2 * u) * MN_DIM;
        const float* ro = xrow + (size_t)(2 * u + 1) * MN_DIM;
        v4f xe = *(const v4f*)(re + 4 * sc);        // aligned 16B
        v4f xo = *(const v4f*)(ro + 4 * sc);        // aligned 16B
        v4f P  = *(const v4f*)(&sphi[4 * sc]);
        v4f ze = xe * P;
        v4f zo = xo * P;

        if (s >= 0) acc += ze;                      // l = 2u

        float lo0 = __shfl_up(zo.z, 1, 64);         // z[4s-2]
        float lo1 = __shfl_up(zo.w, 1, 64);         // z[4s-1]
        if (lane0 && s >= 1) {                      // wave boundary
            v2f xl = *(const v2f*)(ro + 4 * s - 2);
            v2f pl = *(const v2f*)(&sphi[4 * s - 2]);
            lo0 = xl.x * pl.x;
            lo1 = xl.y * pl.y;
        }
        if (s >= 1) { acc.x += lo0;  acc.y += lo1; }   // l = 2u+1, j=0,1
        if (s >= 0) { acc.z += zo.x; acc.w += zo.y; }  // l = 2u+1, j=2,3

        if (t < NT) {
            if (u == t) {
                v2f xl = *(const v2f*)(ro + 510);
                v2f pl = *(const v2f*)(&sphi[510]);
                acct.x += xl.x * pl.x;
                acct.y += xl.y * pl.y;
            } else if (u > t) {
                const int n0 = 512 + 4 * t - 4 * u;  // in [460,508], aligned
                v4f xte = *(const v4f*)(re + n0);
                v4f Pt  = *(const v4f*)(&sphi[n0]);
                acct += xte * Pt;
                v2f xa = *(const v2f*)(ro + n0 - 2);
                v2f pa = *(const v2f*)(&sphi[n0 - 2]);
                v2f xb = *(const v2f*)(ro + n0);
                acct.x += xa.x * pa.x;
                acct.y += xa.y * pa.y;
                acct.z += xb.x * Pt.x;
                acct.w += xb.y * Pt.y;
            }
        }
    }

    // Normal (cached) stores: y2 is re-read by kernel B, keep it in L2/L3.
    float* yrow = y2w + (size_t)bm * YSTRIDE;
    *(v4f*)(yrow + 4 * t) = acc;
    if (t < NT) *(v4f*)(yrow + 512 + 4 * t) = acct;
}

// ------------- Kernel B: out[b,l,m,n] = phi[m,n] * y2[b,m,2l+n] -------------
// Block = (b, 8 consecutive m-rows, ALL 28 l). 1024 threads.
// Stage: 8 y2 rows -> LDS (18.4 KB, contiguous in y2w); phi quad -> regs.
// Stream: 28 iterations, each a 16 KB CONTIGUOUS NT burst, zero global reads.
__global__ __launch_bounds__(1024) void cassi_expand_kernel(
    const float* __restrict__ y2w, const float* __restrict__ phi,
    float* __restrict__ out)
{
    __shared__ __align__(16) float sy[MB][YSTRIDE];   // 18432 B

    const int tid = threadIdx.x;
    const int b   = blockIdx.x >> 6;
    const int m0  = (blockIdx.x & 63) * MB;

    // Stage 8 y2 rows: 8*576 = 4608 floats = 1152 v4f, contiguous in y2w.
    {
        const v4f* src = (const v4f*)(y2w + (size_t)((b << 9) | m0) * YSTRIDE);
        v4f* dst = (v4f*)&sy[0][0];
        dst[tid] = src[tid];
        if (tid < 128) dst[1024 + tid] = src[1024 + tid];
    }

    const int r = tid >> 7;          // row 0..7
    const int t = tid & 127;         // quad 0..127
    const int m = m0 + r;

    // phi quad for this thread, loaded once (coalesced 16B quads).
    v4f pq = *(const v4f*)(phi + (size_t)m * N_DIM + 4 * t);

    __syncthreads();

    const float* syr = &sy[r][0];
    float* oplane = out + (size_t)b * L_DIM * MN_DIM + (size_t)m * N_DIM + 4 * t;

#pragma unroll
    for (int l = 0; l < L_DIM; ++l) {
        v2f ya = *(const v2f*)(syr + 2 * l + 4 * t);     // 8B-aligned LDS
        v2f yb = *(const v2f*)(syr + 2 * l + 4 * t + 2);
        v4f o;
        o.x = pq.x * ya.x;
        o.y = pq.y * ya.y;
        o.z = pq.z * yb.x;
        o.w = pq.w * yb.y;
        __builtin_nontemporal_store(o, (v4f*)(oplane + (size_t)l * MN_DIM));
    }
}

// ---------------- Fallback: proven R6 single-kernel path ----------------
__global__ __launch_bounds__(128) void cassi_fwd_kernel(
    const float* __restrict__ x, const float* __restrict__ phi,
    float* __restrict__ out)
{
    __shared__ __align__(16) float sphi[N_DIM];
    __shared__ __align__(16) float sy2[576];

    const int t  = threadIdx.x;
    const int bm = blockIdx.x;
    const int b  = bm >> 9;
    const int m  = bm & 511;

    const float* xrow = x + (size_t)b * L_DIM * MN_DIM + (size_t)m * N_DIM;

    v4f pq = *(const v4f*)(phi + (size_t)m * N_DIM + 4 * t);
    *(v4f*)&sphi[4 * t] = pq;
    __syncthreads();

    const bool lane0 = ((t & 63) == 0);
    v4f acc  = {0.f, 0.f, 0.f, 0.f};
    v4f acct = {0.f, 0.f, 0.f, 0.f};

#pragma unroll
    for (int u = 0; u < U_DIM; ++u) {
        const int s  = t - u;
        const int sc = s < 0 ? 0 : s;
        const float* re = xrow + (size_t)(2 * u) * MN_DIM;
        const float* ro = xrow + (size_t)(2 * u + 1) * MN_DIM;
        v4f xe = *(const v4f*)(re + 4 * sc);
        v4f xo = *(const v4f*)(ro + 4 * sc);
        v4f P  = *(const v4f*)(&sphi[4 * sc]);
        v4f ze = xe * P;
        v4f zo = xo * P;

        if (s >= 0) acc += ze;

        float lo0 = __shfl_up(zo.z, 1, 64);
        float lo1 = __shfl_up(zo.w, 1, 64);
        if (lane0 && s >= 1) {
            v2f xl = *(const v2f*)(ro + 4 * s - 2);
            v2f pl = *(const v2f*)(&sphi[4 * s - 2]);
            lo0 = xl.x * pl.x;
            lo1 = xl.y * pl.y;
        }
        if (s >= 1) { acc.x += lo0;  acc.y += lo1; }
        if (s >= 0) { acc.z += zo.x; acc.w += zo.y; }

        if (t < NT) {
            if (u == t) {
                v2f xl = *(const v2f*)(ro + 510);
                v2f pl = *(const v2f*)(&sphi[510]);
                acct.x += xl.x * pl.x;
                acct.y += xl.y * pl.y;
            } else if (u > t) {
                const int n0 = 512 + 4 * t - 4 * u;
                v4f xte = *(const v4f*)(re + n0);
                v4f Pt  = *(const v4f*)(&sphi[n0]);
                acct += xte * Pt;
                v2f xa = *(const v2f*)(ro + n0 - 2);
                v2f pa = *(const v2f*)(&sphi[n0 - 2]);
                v2f xb = *(const v2f*)(ro + n0);
                acct.x += xa.x * pa.x;
                acct.y += xa.y * pa.y;
                acct.z += xb.x * Pt.x;
                acct.w += xb.y * Pt.y;
            }
        }
    }

    *(v4f*)&sy2[4 * t] = acc;
    if (t < NT) *(v4f*)&sy2[512 + 4 * t] = acct;
    __syncthreads();

    float* orow = out + (size_t)b * L_DIM * MN_DIM + (size_t)m * N_DIM;
    const float* sy = &sy2[0];
#pragma unroll
    for (int l = 0; l < L_DIM; ++l) {
        v2f ya = *(const v2f*)(sy + 2 * l + 4 * t);
        v2f yb = *(const v2f*)(sy + 2 * l + 4 * t + 2);
        v4f o;
        o.x = pq.x * ya.x;
        o.y = pq.y * ya.y;
        o.z = pq.z * yb.x;
        o.w = pq.w * yb.y;
        __builtin_nontemporal_store(o, (v4f*)(orow + (size_t)l * MN_DIM + 4 * t));
    }
}

extern "C" void kernel_launch(void* const* d_in, const int* in_sizes, int n_in,
                              void* d_out, int out_size, void* d_ws, size_t ws_size,
                              hipStream_t stream) {
    const float* x   = (const float*)d_in[0];
    const float* phi = (const float*)d_in[1];
    float* out       = (float*)d_out;

    const size_t ws_needed = (size_t)B_DIM * M_DIM * YSTRIDE * sizeof(float); // 9.44 MB
    if (d_ws != nullptr && ws_size >= ws_needed) {
        float* y2w = (float*)d_ws;
        cassi_y2_kernel<<<dim3(B_DIM * M_DIM), dim3(128), 0, stream>>>(x, phi, y2w);
        cassi_expand_kernel<<<dim3(B_DIM * (M_DIM / MB)), dim3(1024), 0, stream>>>(y2w, phi, out);
    } else {
        cassi_fwd_kernel<<<dim3(B_DIM * M_DIM), dim3(128), 0, stream>>>(x, phi, out);
    }
}